// Round 1
// baseline (2766.425 us; speedup 1.0000x reference)
//
#include <hip/hip_runtime.h>

#define T_SEQ 188
#define NB    256
#define NIN   128
#define NH    256
#define ZSTR  392   // 384 + 8 pad: 784B row stride, 16B aligned, conflict-free b128

typedef __attribute__((ext_vector_type(8))) short s16x8;
typedef __attribute__((ext_vector_type(4))) short s16x4;
typedef __attribute__((ext_vector_type(4))) float f32x4;

__device__ __forceinline__ short f2bf(float f) {
    union { float f; unsigned u; } v; v.f = f;
    unsigned r = v.u + 0x7fffu + ((v.u >> 16) & 1u);   // RNE
    return (short)(r >> 16);
}

__device__ __forceinline__ float sigf(float x) {
    return __builtin_amdgcn_rcpf(1.0f + __expf(-x));
}
__device__ __forceinline__ float tanh_(float x) {
    // tanh(x) = 1 - 2/(e^{2x}+1); saturates correctly at +-inf
    return 1.0f - 2.0f * __builtin_amdgcn_rcpf(__expf(2.0f * x) + 1.0f);
}

// One WG = one batch-tile of 16 rows for one direction. 16 waves; wave w owns
// hidden units [16w, 16w+16) i.e. gate columns {16w+j, 256+16w+j, 512+16w+j, 768+16w+j}.
// Weights stay in VGPRs as MFMA A-fragments for the whole time loop.
__global__ __launch_bounds__(1024) void lstm_persist(
    const float* __restrict__ x,
    const float* __restrict__ w_ih_f, const float* __restrict__ w_hh_f,
    const float* __restrict__ b_ih_f, const float* __restrict__ b_hh_f,
    const float* __restrict__ w_ih_b, const float* __restrict__ w_hh_b,
    const float* __restrict__ b_ih_b, const float* __restrict__ b_hh_b,
    float* __restrict__ out)
{
    const int bx = blockIdx.x;
    const int d  = bx >> 4;      // direction: 0=fwd, 1=bwd
    const int g  = bx & 15;      // batch tile

    const float* w_ih = d ? w_ih_b : w_ih_f;
    const float* w_hh = d ? w_hh_b : w_hh_f;
    const float* b_ih = d ? b_ih_b : b_ih_f;
    const float* b_hh = d ? b_hh_b : b_hh_f;

    const int tid = threadIdx.x;
    const int w   = tid >> 6;    // wave id 0..15
    const int l   = tid & 63;    // lane
    const int lg  = l >> 4;      // quarter-wave 0..3
    const int lb  = l & 15;      // 0..15

    __shared__ short Z[2][16][ZSTR];   // [buf][batch_row][k], k: 0..127 = x_t, 128..383 = h

    // ---- load weights into registers as A-fragments (bf16) ----
    // A-frag layout (16x16x32): lane l holds A[l&15][8*(l>>4)+e], e=0..7
    s16x8 wf[4][12];
    #pragma unroll
    for (int G = 0; G < 4; ++G) {
        const int gc = G * 256 + 16 * w + lb;          // gate column (row of W)
        #pragma unroll
        for (int kk = 0; kk < 12; ++kk) {
            const int kb = kk * 32 + lg * 8;
            const float* src = (kb < NIN) ? (w_ih + gc * NIN + kb)
                                          : (w_hh + gc * NH + (kb - NIN));
            float4 a  = *(const float4*)(src);
            float4 b2 = *(const float4*)(src + 4);
            s16x8 t;
            t[0] = f2bf(a.x);  t[1] = f2bf(a.y);  t[2] = f2bf(a.z);  t[3] = f2bf(a.w);
            t[4] = f2bf(b2.x); t[5] = f2bf(b2.y); t[6] = f2bf(b2.z); t[7] = f2bf(b2.w);
            wf[G][kk] = t;
        }
    }

    // ---- biases: acc init values. D layout: col=l&15 (batch), row=4*(l>>4)+r (gate col local)
    float bias[4][4];
    #pragma unroll
    for (int G = 0; G < 4; ++G)
        #pragma unroll
        for (int r = 0; r < 4; ++r) {
            const int gc = G * 256 + 16 * w + 4 * lg + r;
            bias[G][r] = b_ih[gc] + b_hh[gc];
        }

    // ---- init Z[0]: h = 0, x = x[t0] ----
    for (int idx = tid; idx < 16 * NH; idx += 1024)
        Z[0][idx >> 8][NIN + (idx & 255)] = 0;
    const int xb = tid >> 6;            // batch row this thread stages
    const int xk = (2 * tid) & 127;     // k pair
    {
        const int t0 = d ? (T_SEQ - 1) : 0;
        float2 xv = *(const float2*)(x + ((size_t)(t0 * NB + g * 16 + xb)) * NIN + xk);
        *(unsigned*)&Z[0][xb][xk] =
            (unsigned)(unsigned short)f2bf(xv.x) | ((unsigned)(unsigned short)f2bf(xv.y) << 16);
    }
    float cst[4] = {0.f, 0.f, 0.f, 0.f};
    __syncthreads();

    float* outbase = out + (size_t)(g * 16) * 512 + d * NH + 16 * w + 4 * lg;

    for (int s = 0; s < T_SEQ; ++s) {
        const int p = s & 1;
        const int t = d ? (T_SEQ - 1 - s) : s;

        // prefetch x for next step (hide HBM latency under MFMA)
        float2 xv;
        const bool havex = (s + 1 < T_SEQ);
        if (havex) {
            const int tn = d ? (T_SEQ - 2 - s) : (s + 1);
            xv = *(const float2*)(x + ((size_t)(tn * NB + g * 16 + xb)) * NIN + xk);
        }

        // B-fragments from LDS: lane l holds Z[k=8*(l>>4)+e][col=l&15] -> contiguous 16B
        s16x8 bf[12];
        #pragma unroll
        for (int kk = 0; kk < 12; ++kk)
            bf[kk] = *(const s16x8*)&Z[p][lb][kk * 32 + lg * 8];

        // MFMA: gates[64 x 16] per wave, f32 accum init from biases
        f32x4 acc[4];
        #pragma unroll
        for (int G = 0; G < 4; ++G) {
            acc[G][0] = bias[G][0]; acc[G][1] = bias[G][1];
            acc[G][2] = bias[G][2]; acc[G][3] = bias[G][3];
        }
        #pragma unroll
        for (int kk = 0; kk < 12; ++kk) {
            acc[0] = __builtin_amdgcn_mfma_f32_16x16x32_bf16(wf[0][kk], bf[kk], acc[0], 0, 0, 0);
            acc[1] = __builtin_amdgcn_mfma_f32_16x16x32_bf16(wf[1][kk], bf[kk], acc[1], 0, 0, 0);
            acc[2] = __builtin_amdgcn_mfma_f32_16x16x32_bf16(wf[2][kk], bf[kk], acc[2], 0, 0, 0);
            acc[3] = __builtin_amdgcn_mfma_f32_16x16x32_bf16(wf[3][kk], bf[kk], acc[3], 0, 0, 0);
        }

        // gates -> c,h  (4 hidden units per lane, batch col = lb)
        float4 hout;
        s16x4 hbf;
        #pragma unroll
        for (int r = 0; r < 4; ++r) {
            const float iv = sigf(acc[0][r]);
            const float fv = sigf(acc[1][r]);
            const float gv = tanh_(acc[2][r]);
            const float ov = sigf(acc[3][r]);
            const float c  = fv * cst[r] + iv * gv;
            cst[r] = c;
            const float h = ov * tanh_(c);
            (&hout.x)[r] = h;
            hbf[r] = f2bf(h);
        }

        // h -> next Z buffer (bf16), 8B store, conflict-free
        *(s16x4*)&Z[p ^ 1][lb][NIN + 16 * w + 4 * lg] = hbf;
        // x_{t+1} -> next Z buffer
        if (havex)
            *(unsigned*)&Z[p ^ 1][xb][xk] =
                (unsigned)(unsigned short)f2bf(xv.x) | ((unsigned)(unsigned short)f2bf(xv.y) << 16);

        // output: per wave, each batch row gets a contiguous 64B j-range -> coalesced
        *(f32x4*)(outbase + (size_t)t * NB * 512 + lb * 512) = *(f32x4*)&hout;

        __syncthreads();
    }
}

extern "C" void kernel_launch(void* const* d_in, const int* in_sizes, int n_in,
                              void* d_out, int out_size, void* d_ws, size_t ws_size,
                              hipStream_t stream) {
    const float* x      = (const float*)d_in[0];
    const float* w_ih_f = (const float*)d_in[1];
    const float* w_hh_f = (const float*)d_in[2];
    const float* b_ih_f = (const float*)d_in[3];
    const float* b_hh_f = (const float*)d_in[4];
    const float* w_ih_b = (const float*)d_in[5];
    const float* w_hh_b = (const float*)d_in[6];
    const float* b_ih_b = (const float*)d_in[7];
    const float* b_hh_b = (const float*)d_in[8];
    float* out = (float*)d_out;

    lstm_persist<<<dim3(32), dim3(1024), 0, stream>>>(
        x, w_ih_f, w_hh_f, b_ih_f, b_hh_f, w_ih_b, w_hh_b, b_ih_b, b_hh_b, out);
}

// Round 2
// 1158.401 us; speedup vs baseline: 2.3881x; 2.3881x over previous
//
#include <hip/hip_runtime.h>

#define T_SEQ 188
#define NB    256
#define NIN   128
#define NH    256
#define ZSTR  392   // 384 + 8 pad shorts; row stride 784 B (16B-aligned)

typedef __attribute__((ext_vector_type(8))) short s16x8;
typedef __attribute__((ext_vector_type(4))) short s16x4;
typedef __attribute__((ext_vector_type(4))) float f32x4;

__device__ __forceinline__ short f2bf(float f) {
    union { float f; unsigned u; } v; v.f = f;
    unsigned r = v.u + 0x7fffu + ((v.u >> 16) & 1u);   // RNE
    return (short)(r >> 16);
}
__device__ __forceinline__ float sigf(float x) {
    return __builtin_amdgcn_rcpf(1.0f + __expf(-x));
}
__device__ __forceinline__ float tanh_(float x) {
    return 1.0f - 2.0f * __builtin_amdgcn_rcpf(__expf(2.0f * x) + 1.0f);
}

// WG b: dir = b>>5, hidden-half hh = (b>>4)&1, batch-tile bt = b&15.
// Partner = b^16 (same dir, same bt, other half; same XCD under %8 round-robin).
// 8 waves; wave w owns hidden units [hh*128 + 16w, +16) for all 4 gates.
// Its 48 weight A-fragments (192 VGPRs) stay register-resident the whole run.
// K layout in LDS Z row: [0,128)=x_t, [128,384)=h(full). Compute order permuted
// per-WG: tiles 0..3 = x, 4..7 = own h-half, 8..11 = partner h-half (arrives
// mid-step via d_out + flag handshake).
__global__ __launch_bounds__(512, 2) void lstm_persist(
    const float* __restrict__ x,
    const float* __restrict__ w_ih_f, const float* __restrict__ w_hh_f,
    const float* __restrict__ b_ih_f, const float* __restrict__ b_hh_f,
    const float* __restrict__ w_ih_b, const float* __restrict__ w_hh_b,
    const float* __restrict__ b_ih_b, const float* __restrict__ b_hh_b,
    float* __restrict__ out, unsigned* __restrict__ flags)
{
    const int b  = blockIdx.x;
    const int d  = b >> 5;
    const int hh = (b >> 4) & 1;
    const int bt = b & 15;
    const int pb = b ^ 16;
    const int po = 1 - hh;

    const float* w_ih = d ? w_ih_b : w_ih_f;
    const float* w_hh = d ? w_hh_b : w_hh_f;
    const float* b_ih = d ? b_ih_b : b_ih_f;
    const float* b_hh = d ? b_hh_b : b_hh_f;

    const int tid = threadIdx.x;
    const int w   = tid >> 6;
    const int l   = tid & 63;
    const int lg  = l >> 4;
    const int lb  = l & 15;
    const int hbase = hh * 128 + 16 * w;

    __shared__ short Z[2][16][ZSTR];
    __shared__ float biasL[8][4][16];

    // short-index offsets into a Z row; immediates (+32*j) fold into ds_read offset
    const int off_x   = lg * 8;                     // tiles 0..3: + 32*kk
    const int off_own = (4 + 4 * hh) * 32 + lg * 8; // tiles 4..7
    const int off_par = (4 + 4 * po) * 32 + lg * 8; // tiles 8..11

    // ---- weights -> registers as 16x16x32 A-fragments (lane: A[lb][8*lg+e]) ----
    s16x8 wf[4][12];
    #pragma unroll
    for (int G = 0; G < 4; ++G) {
        const int gc = G * 256 + hbase + lb;   // gate column = row of W
        #pragma unroll
        for (int kkidx = 0; kkidx < 12; ++kkidx) {
            const int kb = (kkidx < 4) ? (off_x + 32 * kkidx)
                         : (kkidx < 8) ? (off_own + 32 * (kkidx - 4))
                                       : (off_par + 32 * (kkidx - 8));
            const float* src = (kb < NIN) ? (w_ih + (size_t)gc * NIN + kb)
                                          : (w_hh + (size_t)gc * NH + (kb - NIN));
            float4 a  = *(const float4*)(src);
            float4 b2 = *(const float4*)(src + 4);
            s16x8 tv;
            tv[0] = f2bf(a.x);  tv[1] = f2bf(a.y);  tv[2] = f2bf(a.z);  tv[3] = f2bf(a.w);
            tv[4] = f2bf(b2.x); tv[5] = f2bf(b2.y); tv[6] = f2bf(b2.z); tv[7] = f2bf(b2.w);
            wf[G][kkidx] = tv;
        }
    }

    // ---- biases -> LDS (saves 16 VGPRs); lane (lg,lb) writes [w][lb>>2][4lg+(lb&3)]
    {
        const int G = lb >> 2, r = lb & 3;
        const int gcr = G * 256 + hbase + 4 * lg + r;
        biasL[w][G][4 * lg + r] = b_ih[gcr] + b_hh[gcr];
    }

    const int srow = tid >> 5;         // staging: batch row 0..15
    const int sk4  = (tid & 31) * 4;   // staging: 4-elem column group

    // ---- init Z[0]: h = 0 (both halves), x = x[t0] ----
    {
        s16x8 zz; 
        #pragma unroll
        for (int i = 0; i < 8; ++i) zz[i] = 0;
        *(s16x8*)&Z[0][srow][NIN + (tid & 31) * 8] = zz;
        const int t0 = d ? (T_SEQ - 1) : 0;
        float4 xv0 = *(const float4*)(x + ((size_t)(t0 * NB + bt * 16 + srow)) * NIN + sk4);
        s16x4 xp;
        xp[0] = f2bf(xv0.x); xp[1] = f2bf(xv0.y); xp[2] = f2bf(xv0.z); xp[3] = f2bf(xv0.w);
        *(s16x4*)&Z[0][srow][sk4] = xp;
    }
    float cst[4] = {0.f, 0.f, 0.f, 0.f};
    __syncthreads();

    unsigned* myflag = flags + b * 16;   // 64-B spacing, no false sharing
    unsigned* pflag  = flags + pb * 16;

    float* outp = out + (size_t)(bt * 16) * 512 + d * 256 + hbase + 4 * lg;

    for (int s = 0; s < T_SEQ; ++s) {
        const int p = s & 1;
        const int t = d ? (T_SEQ - 1 - s) : s;

        // prefetch next x (consumed at end of step)
        float4 xv;
        const bool havex = (s + 1 < T_SEQ);
        if (havex) {
            const int tn = d ? (T_SEQ - 2 - s) : (s + 1);
            xv = *(const float4*)(x + ((size_t)(tn * NB + bt * 16 + srow)) * NIN + sk4);
        }

        f32x4 acc[4];
        #pragma unroll
        for (int G = 0; G < 4; ++G)
            acc[G] = *(const f32x4*)&biasL[w][G][4 * lg];

        const short* zrow = &Z[p][lb][0];

        // phase B: x tiles + own-half tiles (locally available)
        #pragma unroll
        for (int kk = 0; kk < 4; ++kk) {
            s16x8 bfv = *(const s16x8*)(zrow + off_x + 32 * kk);
            acc[0] = __builtin_amdgcn_mfma_f32_16x16x32_bf16(wf[0][kk], bfv, acc[0], 0, 0, 0);
            acc[1] = __builtin_amdgcn_mfma_f32_16x16x32_bf16(wf[1][kk], bfv, acc[1], 0, 0, 0);
            acc[2] = __builtin_amdgcn_mfma_f32_16x16x32_bf16(wf[2][kk], bfv, acc[2], 0, 0, 0);
            acc[3] = __builtin_amdgcn_mfma_f32_16x16x32_bf16(wf[3][kk], bfv, acc[3], 0, 0, 0);
        }
        #pragma unroll
        for (int kk = 0; kk < 4; ++kk) {
            s16x8 bfv = *(const s16x8*)(zrow + off_own + 32 * kk);
            acc[0] = __builtin_amdgcn_mfma_f32_16x16x32_bf16(wf[0][4 + kk], bfv, acc[0], 0, 0, 0);
            acc[1] = __builtin_amdgcn_mfma_f32_16x16x32_bf16(wf[1][4 + kk], bfv, acc[1], 0, 0, 0);
            acc[2] = __builtin_amdgcn_mfma_f32_16x16x32_bf16(wf[2][4 + kk], bfv, acc[2], 0, 0, 0);
            acc[3] = __builtin_amdgcn_mfma_f32_16x16x32_bf16(wf[3][4 + kk], bfv, acc[3], 0, 0, 0);
        }

        // phase C: acquire partner h-half (produced end of their step s-1, in d_out)
        if (s > 0) {
            const unsigned want = (unsigned)s;
            while (__hip_atomic_load(pflag, __ATOMIC_RELAXED, __HIP_MEMORY_SCOPE_AGENT) < want)
                __builtin_amdgcn_s_sleep(1);
            __builtin_amdgcn_fence(__ATOMIC_ACQUIRE, "agent");
            const int tprev = d ? (T_SEQ - s) : (s - 1);
            float4 pv = *(const float4*)(out + (size_t)tprev * NB * 512
                         + (size_t)(bt * 16 + srow) * 512 + d * 256 + po * 128 + sk4);
            s16x4 pp;
            pp[0] = f2bf(pv.x); pp[1] = f2bf(pv.y); pp[2] = f2bf(pv.z); pp[3] = f2bf(pv.w);
            *(s16x4*)&Z[p][srow][NIN + po * 128 + sk4] = pp;
        }
        __syncthreads();   // barrier 1: partner tiles in LDS

        // phase D: partner-half tiles
        #pragma unroll
        for (int kk = 0; kk < 4; ++kk) {
            s16x8 bfv = *(const s16x8*)(zrow + off_par + 32 * kk);
            acc[0] = __builtin_amdgcn_mfma_f32_16x16x32_bf16(wf[0][8 + kk], bfv, acc[0], 0, 0, 0);
            acc[1] = __builtin_amdgcn_mfma_f32_16x16x32_bf16(wf[1][8 + kk], bfv, acc[1], 0, 0, 0);
            acc[2] = __builtin_amdgcn_mfma_f32_16x16x32_bf16(wf[2][8 + kk], bfv, acc[2], 0, 0, 0);
            acc[3] = __builtin_amdgcn_mfma_f32_16x16x32_bf16(wf[3][8 + kk], bfv, acc[3], 0, 0, 0);
        }

        // gates -> c,h (lane: 4 hidden units, batch col lb)
        float4 hout;
        s16x4 hbf;
        #pragma unroll
        for (int r = 0; r < 4; ++r) {
            const float iv = sigf(acc[0][r]);
            const float fv = sigf(acc[1][r]);
            const float gv = tanh_(acc[2][r]);
            const float ov = sigf(acc[3][r]);
            const float c  = fv * cst[r] + iv * gv;
            cst[r] = c;
            const float h = ov * tanh_(c);
            (&hout.x)[r] = h;
            hbf[r] = f2bf(h);
        }

        // own h -> next Z buffer; x_{t+1} -> next Z buffer; h -> out (f32)
        *(s16x4*)&Z[p ^ 1][lb][NIN + hbase + 4 * lg] = hbf;
        if (havex) {
            s16x4 xp;
            xp[0] = f2bf(xv.x); xp[1] = f2bf(xv.y); xp[2] = f2bf(xv.z); xp[3] = f2bf(xv.w);
            *(s16x4*)&Z[p ^ 1][srow][sk4] = xp;
        }
        *(f32x4*)(outp + (size_t)t * NB * 512 + lb * 512) = *(f32x4*)&hout;

        __syncthreads();   // barrier 2: drains vmcnt (out stores in L2) + Z[p^1] ready
        if (tid == 0 && s + 1 < T_SEQ)
            __hip_atomic_store(myflag, (unsigned)(s + 1),
                               __ATOMIC_RELEASE, __HIP_MEMORY_SCOPE_AGENT);
    }
}

extern "C" void kernel_launch(void* const* d_in, const int* in_sizes, int n_in,
                              void* d_out, int out_size, void* d_ws, size_t ws_size,
                              hipStream_t stream) {
    const float* x      = (const float*)d_in[0];
    const float* w_ih_f = (const float*)d_in[1];
    const float* w_hh_f = (const float*)d_in[2];
    const float* b_ih_f = (const float*)d_in[3];
    const float* b_hh_f = (const float*)d_in[4];
    const float* w_ih_b = (const float*)d_in[5];
    const float* w_hh_b = (const float*)d_in[6];
    const float* b_ih_b = (const float*)d_in[7];
    const float* b_hh_b = (const float*)d_in[8];
    float* out = (float*)d_out;
    unsigned* flags = (unsigned*)d_ws;

    // zero the 64 x 64B flag slots each launch (replay-safe; graph-capturable)
    hipMemsetAsync(flags, 0, 64 * 16 * sizeof(unsigned), stream);

    lstm_persist<<<dim3(64), dim3(512), 0, stream>>>(
        x, w_ih_f, w_hh_f, b_ih_f, b_hh_f, w_ih_b, w_hh_b, b_ih_b, b_hh_b, out, flags);
}

// Round 3
// 829.337 us; speedup vs baseline: 3.3357x; 1.3968x over previous
//
#include <hip/hip_runtime.h>

#define T_SEQ 188
#define NB    256
#define NIN   128
#define NH    256
#define ZSTR  264   // 128 x + 128 own-h + 8 pad shorts; 528 B row stride

typedef __attribute__((ext_vector_type(8))) short s16x8;
typedef __attribute__((ext_vector_type(4))) short s16x4;
typedef __attribute__((ext_vector_type(4))) float f32x4;

__device__ __forceinline__ short f2bf(float f) {
    union { float f; unsigned u; } v; v.f = f;
    unsigned r = v.u + 0x7fffu + ((v.u >> 16) & 1u);   // RNE
    return (short)(r >> 16);
}
__device__ __forceinline__ float sigf(float x) {
    return __builtin_amdgcn_rcpf(1.0f + __expf(-x));
}
__device__ __forceinline__ float tanh_(float x) {
    return 1.0f - 2.0f * __builtin_amdgcn_rcpf(__expf(2.0f * x) + 1.0f);
}

// WG b: dir = b>>5, hidden-half hh = (b>>4)&1, batch-tile bt = b&15. Partner = b^16.
// 8 waves; wave w owns hidden units [hh*128+16w, +16) for all 4 gates; its 48
// bf16 A-fragments (192 VGPRs) are register-resident for the whole sequence.
// Per step: 8 local K-tiles (x + own h-half) from LDS, 4 partner K-tiles loaded
// straight into B-fragments from an IC-coherent ping-pong buffer in d_ws
// (relaxed agent atomics, sc0|sc1 — NO fences, NO L2 wb/inv).
__global__ __launch_bounds__(512, 2) void lstm_persist(
    const float* __restrict__ x,
    const float* __restrict__ w_ih_f, const float* __restrict__ w_hh_f,
    const float* __restrict__ b_ih_f, const float* __restrict__ b_hh_f,
    const float* __restrict__ w_ih_b, const float* __restrict__ w_hh_b,
    const float* __restrict__ b_ih_b, const float* __restrict__ b_hh_b,
    float* __restrict__ out, unsigned* __restrict__ flags,
    unsigned long long* __restrict__ xchg)
{
    const int b  = blockIdx.x;
    const int d  = b >> 5;
    const int hh = (b >> 4) & 1;
    const int bt = b & 15;
    const int pb = b ^ 16;

    const float* w_ih = d ? w_ih_b : w_ih_f;
    const float* w_hh = d ? w_hh_b : w_hh_f;
    const float* b_ih = d ? b_ih_b : b_ih_f;
    const float* b_hh = d ? b_hh_b : b_hh_f;

    const int tid = threadIdx.x;
    const int w   = tid >> 6;
    const int l   = tid & 63;
    const int lg  = l >> 4;
    const int lb  = l & 15;
    const int hbase = hh * 128 + 16 * w;
    const int po = 1 - hh;

    __shared__ short Z[2][16][ZSTR];     // row: [0,128)=x_t, [128,256)=own h-half (local cols)
    __shared__ float biasL[8][4][16];

    const int off_x   = lg * 8;          // x tiles: + 32*kk
    const int off_own = NIN + lg * 8;    // own-h tiles: + 32*kk

    // ---- weights -> registers as 16x16x32 A-fragments (lane: A[lb][8*lg+e]) ----
    // K-tile order: 0..3 = x, 4..7 = own h-half, 8..11 = partner h-half
    s16x8 wf[4][12];
    #pragma unroll
    for (int G = 0; G < 4; ++G) {
        const int gc = G * 256 + hbase + lb;   // gate row of W
        #pragma unroll
        for (int kkidx = 0; kkidx < 12; ++kkidx) {
            const int kglob = (kkidx < 4)  ? (32 * kkidx + 8 * lg)
                            : (kkidx < 8)  ? (NIN + hh * 128 + 32 * (kkidx - 4) + 8 * lg)
                                           : (NIN + po * 128 + 32 * (kkidx - 8) + 8 * lg);
            const float* src = (kglob < NIN) ? (w_ih + (size_t)gc * NIN + kglob)
                                             : (w_hh + (size_t)gc * NH + (kglob - NIN));
            float4 a  = *(const float4*)(src);
            float4 b2 = *(const float4*)(src + 4);
            s16x8 tv;
            tv[0] = f2bf(a.x);  tv[1] = f2bf(a.y);  tv[2] = f2bf(a.z);  tv[3] = f2bf(a.w);
            tv[4] = f2bf(b2.x); tv[5] = f2bf(b2.y); tv[6] = f2bf(b2.z); tv[7] = f2bf(b2.w);
            wf[G][kkidx] = tv;
        }
    }

    // ---- biases -> LDS
    {
        const int G = lb >> 2, r = lb & 3;
        const int gcr = G * 256 + hbase + 4 * lg + r;
        biasL[w][G][4 * lg + r] = b_ih[gcr] + b_hh[gcr];
    }

    const int srow = tid >> 5;          // staging batch row
    const int sk4  = (tid & 31) * 4;    // staging col group (x region)

    // ---- init Z[0]: own h = 0, x = x[t0]
    {
        s16x4 zz; zz[0] = 0; zz[1] = 0; zz[2] = 0; zz[3] = 0;
        *(s16x4*)&Z[0][srow][NIN + (tid & 31) * 4] = zz;
        const int t0 = d ? (T_SEQ - 1) : 0;
        float4 xv0 = *(const float4*)(x + ((size_t)(t0 * NB + bt * 16 + srow)) * NIN + sk4);
        s16x4 xp;
        xp[0] = f2bf(xv0.x); xp[1] = f2bf(xv0.y); xp[2] = f2bf(xv0.z); xp[3] = f2bf(xv0.w);
        *(s16x4*)&Z[0][srow][sk4] = xp;
    }
    float cst[4] = {0.f, 0.f, 0.f, 0.f};
    __syncthreads();

    unsigned* myflag = flags + b * 16;
    unsigned* pflag  = flags + pb * 16;

    float* outp = out + (size_t)(bt * 16) * 512 + d * 256 + hbase + 4 * lg;

    for (int s = 0; s < T_SEQ; ++s) {
        const int p = s & 1;
        const int t = d ? (T_SEQ - 1 - s) : s;

        // ---- partner B-fragments: poll flag, then load straight from IC
        s16x8 ptile[4];
        if (s > 0) {
            const unsigned want = (unsigned)s;
            while (__hip_atomic_load(pflag, __ATOMIC_RELAXED, __HIP_MEMORY_SCOPE_AGENT) < want)
                __builtin_amdgcn_s_sleep(1);
            const unsigned long long* pbase =
                xchg + ((size_t)(pb * 2 + p) * 16 + lb) * 32 + 2 * lg;
            #pragma unroll
            for (int kk = 0; kk < 4; ++kk) {
                union { s16x8 v; unsigned long long u[2]; } tmp;
                tmp.u[0] = __hip_atomic_load(pbase + 8 * kk,
                                             __ATOMIC_RELAXED, __HIP_MEMORY_SCOPE_AGENT);
                tmp.u[1] = __hip_atomic_load(pbase + 8 * kk + 1,
                                             __ATOMIC_RELAXED, __HIP_MEMORY_SCOPE_AGENT);
                ptile[kk] = tmp.v;
            }
        }

        // ---- prefetch next x
        float4 xv;
        const bool havex = (s + 1 < T_SEQ);
        if (havex) {
            const int tn = d ? (T_SEQ - 2 - s) : (s + 1);
            xv = *(const float4*)(x + ((size_t)(tn * NB + bt * 16 + srow)) * NIN + sk4);
        }

        f32x4 acc[4];
        #pragma unroll
        for (int G = 0; G < 4; ++G)
            acc[G] = *(const f32x4*)&biasL[w][G][4 * lg];

        const short* zrow = &Z[p][lb][0];

        // ---- phase B: x tiles + own-half tiles (LDS; partner loads in flight)
        #pragma unroll
        for (int kk = 0; kk < 4; ++kk) {
            s16x8 bfv = *(const s16x8*)(zrow + off_x + 32 * kk);
            acc[0] = __builtin_amdgcn_mfma_f32_16x16x32_bf16(wf[0][kk], bfv, acc[0], 0, 0, 0);
            acc[1] = __builtin_amdgcn_mfma_f32_16x16x32_bf16(wf[1][kk], bfv, acc[1], 0, 0, 0);
            acc[2] = __builtin_amdgcn_mfma_f32_16x16x32_bf16(wf[2][kk], bfv, acc[2], 0, 0, 0);
            acc[3] = __builtin_amdgcn_mfma_f32_16x16x32_bf16(wf[3][kk], bfv, acc[3], 0, 0, 0);
        }
        #pragma unroll
        for (int kk = 0; kk < 4; ++kk) {
            s16x8 bfv = *(const s16x8*)(zrow + off_own + 32 * kk);
            acc[0] = __builtin_amdgcn_mfma_f32_16x16x32_bf16(wf[0][4 + kk], bfv, acc[0], 0, 0, 0);
            acc[1] = __builtin_amdgcn_mfma_f32_16x16x32_bf16(wf[1][4 + kk], bfv, acc[1], 0, 0, 0);
            acc[2] = __builtin_amdgcn_mfma_f32_16x16x32_bf16(wf[2][4 + kk], bfv, acc[2], 0, 0, 0);
            acc[3] = __builtin_amdgcn_mfma_f32_16x16x32_bf16(wf[3][4 + kk], bfv, acc[3], 0, 0, 0);
        }

        // ---- phase D: partner tiles (register B-fragments)
        if (s > 0) {
            #pragma unroll
            for (int kk = 0; kk < 4; ++kk) {
                acc[0] = __builtin_amdgcn_mfma_f32_16x16x32_bf16(wf[0][8 + kk], ptile[kk], acc[0], 0, 0, 0);
                acc[1] = __builtin_amdgcn_mfma_f32_16x16x32_bf16(wf[1][8 + kk], ptile[kk], acc[1], 0, 0, 0);
                acc[2] = __builtin_amdgcn_mfma_f32_16x16x32_bf16(wf[2][8 + kk], ptile[kk], acc[2], 0, 0, 0);
                acc[3] = __builtin_amdgcn_mfma_f32_16x16x32_bf16(wf[3][8 + kk], ptile[kk], acc[3], 0, 0, 0);
            }
        }

        // ---- gates -> c,h (lane: 4 hidden units, batch col lb)
        float4 hout;
        s16x4 hbf;
        #pragma unroll
        for (int r = 0; r < 4; ++r) {
            const float iv = sigf(acc[0][r]);
            const float fv = sigf(acc[1][r]);
            const float gv = tanh_(acc[2][r]);
            const float ov = sigf(acc[3][r]);
            const float c  = fv * cst[r] + iv * gv;
            cst[r] = c;
            const float h = ov * tanh_(c);
            (&hout.x)[r] = h;
            hbf[r] = f2bf(h);
        }

        // ---- publish own h to partner (IC-coherent, no fence)
        {
            union { s16x4 v; unsigned long long u; } hx; hx.v = hbf;
            __hip_atomic_store(
                xchg + ((size_t)(b * 2 + ((s + 1) & 1)) * 16 + lb) * 32 + 4 * w + lg,
                hx.u, __ATOMIC_RELAXED, __HIP_MEMORY_SCOPE_AGENT);
        }
        // ---- own h + next x -> next Z buffer; h -> out
        *(s16x4*)&Z[p ^ 1][lb][NIN + 16 * w + 4 * lg] = hbf;
        if (havex) {
            s16x4 xp;
            xp[0] = f2bf(xv.x); xp[1] = f2bf(xv.y); xp[2] = f2bf(xv.z); xp[3] = f2bf(xv.w);
            *(s16x4*)&Z[p ^ 1][srow][sk4] = xp;
        }
        *(f32x4*)(outp + (size_t)t * NB * 512 + lb * 512) = *(f32x4*)&hout;

        __syncthreads();   // drains vmcnt (xchg stores ack'd at IC) + Z[p^1] ready
        if (tid == 0 && s + 1 < T_SEQ)
            __hip_atomic_store(myflag, (unsigned)(s + 1),
                               __ATOMIC_RELAXED, __HIP_MEMORY_SCOPE_AGENT);
    }
}

extern "C" void kernel_launch(void* const* d_in, const int* in_sizes, int n_in,
                              void* d_out, int out_size, void* d_ws, size_t ws_size,
                              hipStream_t stream) {
    const float* x      = (const float*)d_in[0];
    const float* w_ih_f = (const float*)d_in[1];
    const float* w_hh_f = (const float*)d_in[2];
    const float* b_ih_f = (const float*)d_in[3];
    const float* b_hh_f = (const float*)d_in[4];
    const float* w_ih_b = (const float*)d_in[5];
    const float* w_hh_b = (const float*)d_in[6];
    const float* b_ih_b = (const float*)d_in[7];
    const float* b_hh_b = (const float*)d_in[8];
    float* out = (float*)d_out;

    unsigned* flags = (unsigned*)d_ws;                                  // 4 KB
    unsigned long long* xchg = (unsigned long long*)((char*)d_ws + 4096); // 512 KB

    hipMemsetAsync(flags, 0, 4096, stream);   // replay-safe flag reset

    lstm_persist<<<dim3(64), dim3(512), 0, stream>>>(
        x, w_ih_f, w_hh_f, b_ih_f, b_hh_f, w_ih_b, w_hh_b, b_ih_b, b_hh_b,
        out, flags, xchg);
}